// Round 12
// baseline (358.515 us; speedup 1.0000x reference)
//
#include <hip/hip_runtime.h>

// R12: identical to R11 — acquisition timed out; the MFMA hi/lo-split GEMM
// diff is still unmeasured. Re-audited layouts (A/B frag, C/D, in-place
// safety) offline; measurement attempt #2.

#define N_NODES 100000
#define N_EDGES 800000
#define D 128
#define BN_EPS 1e-5f
#define SCAN_NB 98  // ceil(100000/1024)

using bf16x8 = __attribute__((ext_vector_type(8))) short;
using f32x4 = __attribute__((ext_vector_type(4))) float;

__device__ __forceinline__ unsigned short f2b(float f) {  // fp32->bf16 RNE
    unsigned u = __float_as_uint(f);
    unsigned r = ((u >> 16) & 1u) + 0x7fffu;
    return (unsigned short)((u + r) >> 16);
}
__device__ __forceinline__ float b2f(unsigned short h) {
    return __uint_as_float(((unsigned)h) << 16);
}

// ---------------- edge-index dtype hedge (int32 vs int64) ----------------
__global__ void detect_i64(const unsigned int* ei, int* flag) {
    __shared__ int nonzero;
    if (threadIdx.x == 0) nonzero = 0;
    __syncthreads();
    int local = 0;
    for (int i = threadIdx.x; i < 2048; i += 256)
        if (ei[2 * i + 1] != 0u) local = 1;
    if (local) atomicOr(&nonzero, 1);
    __syncthreads();
    if (threadIdx.x == 0) *flag = (nonzero == 0) ? 1 : 0;  // 1 => int64
}

__device__ __forceinline__ int edge_at(const void* ei, int is64, long long pos) {
    if (is64) return (int)((const long long*)ei)[pos];
    return ((const int*)ei)[pos];
}

// ---------------- degree histogram (int atomics) ----------------
__global__ void count_deg_i(const void* ei, const int* __restrict__ flag,
                            int* __restrict__ deg) {
    int is64 = *flag;
    for (int i = blockIdx.x * blockDim.x + threadIdx.x; i < N_EDGES;
         i += gridDim.x * blockDim.x) {
        int d = edge_at(ei, is64, (long long)N_EDGES + i);
        atomicAdd(&deg[d], 1);
    }
}

// ---------------- 3-kernel exclusive scan over deg -> rp ----------------
__global__ __launch_bounds__(256) void scan1(const int* __restrict__ deg,
                                             int* __restrict__ rp,
                                             int* __restrict__ bsum) {
    __shared__ int wsum[4];
    int tid = threadIdx.x;
    int base = blockIdx.x * 1024;
    int v[4];
#pragma unroll
    for (int i = 0; i < 4; ++i) {
        int idx = base + tid * 4 + i;
        v[i] = (idx < N_NODES) ? deg[idx] : 0;
    }
    int tsum = v[0] + v[1] + v[2] + v[3];
    int lane = tid & 63;
    int incl = tsum;
#pragma unroll
    for (int off = 1; off < 64; off <<= 1) {
        int n = __shfl_up(incl, off, 64);
        if (lane >= off) incl += n;
    }
    int wid = tid >> 6;
    if (lane == 63) wsum[wid] = incl;
    __syncthreads();
    int woff = 0;
    for (int w = 0; w < wid; ++w) woff += wsum[w];
    int run = woff + incl - tsum;  // exclusive prefix for this thread
#pragma unroll
    for (int i = 0; i < 4; ++i) {
        int idx = base + tid * 4 + i;
        if (idx < N_NODES) rp[idx] = run;
        run += v[i];
    }
    if (tid == 255) bsum[blockIdx.x] = woff + incl;  // block total
}

__global__ void scan2(int* __restrict__ bsum, int* __restrict__ rp) {
    __shared__ int s[128];
    int t = threadIdx.x;
    if (t < SCAN_NB) s[t] = bsum[t];
    __syncthreads();
    if (t == 0) {
        int run = 0;
        for (int i = 0; i < SCAN_NB; ++i) { int x = s[i]; s[i] = run; run += x; }
        rp[N_NODES] = N_EDGES;
    }
    __syncthreads();
    if (t < SCAN_NB) bsum[t] = s[t];
}

__global__ void scan3(int* __restrict__ rp, const int* __restrict__ bsum,
                      int* __restrict__ fp, const int* __restrict__ deg,
                      float* __restrict__ dis) {
    int idx = blockIdx.x * 256 + threadIdx.x;
    if (idx < N_NODES) {
        int v = rp[idx] + bsum[idx >> 10];
        rp[idx] = v;
        fp[idx] = v;
        dis[idx] = rsqrtf((float)deg[idx] + 1.0f);  // +1 self loop
    }
}

// ---------------- bucket fill: eb[rp[d]..] = (src, dis[s]*dis[d]) ----------------
__global__ void fill_csr(const void* ei, const int* __restrict__ flag,
                         int* __restrict__ fp, const float* __restrict__ dis,
                         int2* __restrict__ eb) {
    int is64 = *flag;
    for (int e = blockIdx.x * blockDim.x + threadIdx.x; e < N_EDGES;
         e += gridDim.x * blockDim.x) {
        int s = edge_at(ei, is64, e);
        int d = edge_at(ei, is64, (long long)N_EDGES + e);
        float coef = dis[s] * dis[d];
        int pos = atomicAdd(&fp[d], 1);
        eb[pos] = make_int2(s, __float_as_int(coef));
    }
}

// ---------------- W fragment tables: bf16 hi/lo, MFMA-B-fragment order ----------
// slot = t*512 + c*64 + l : lane l of k-tile t, col-tile c; 8 bf16 each:
// W[t*32 + (l>>4)*8 + j][c*16 + (l&15)], j=0..7.
__global__ void prep_w(const float* __restrict__ Wm, bf16x8* __restrict__ Whi,
                       bf16x8* __restrict__ Wlo) {
    for (int slot = threadIdx.x; slot < 2048; slot += 256) {
        int t = slot >> 9;
        int rem = slot & 511;
        int c = rem >> 6;
        int l = rem & 63;
        int k0 = t * 32 + ((l >> 4) << 3);
        int col = c * 16 + (l & 15);
        bf16x8 hi, lo;
#pragma unroll
        for (int j = 0; j < 8; ++j) {
            float v = Wm[(size_t)(k0 + j) * 128 + col];
            unsigned short h = f2b(v);
            hi[j] = (short)h;
            lo[j] = (short)f2b(v - b2f(h));
        }
        Whi[slot] = hi;
        Wlo[slot] = lo;
    }
}

// ---------------- gather: agg row -> bf16 hi[128]+lo[128] (512B) in d_out ------
// one 64-lane wave per node, float2 per lane; 4-deep edge pipeline.
__global__ __launch_bounds__(256) void gather_x(const int* __restrict__ rp,
                                                const int2* __restrict__ eb,
                                                const float* __restrict__ dis,
                                                const float* __restrict__ x,
                                                void* __restrict__ aggx) {
    int lane = threadIdx.x & 63;
    int wid = threadIdx.x >> 6;
    const float2* x2 = (const float2*)x;
    for (int node = blockIdx.x * 4 + wid; node < N_NODES;
         node += gridDim.x * 4) {
        int beg = rp[node], end = rp[node + 1];
        float dd = dis[node];
        float2 xv = x2[(size_t)node * 64 + lane];
        float c2 = dd * dd;
        float a0 = xv.x * c2, a1 = xv.y * c2;
        int j = beg;
        for (; j + 4 <= end; j += 4) {
            int2 e0 = eb[j], e1 = eb[j + 1], e2 = eb[j + 2], e3 = eb[j + 3];
            float2 v0 = x2[(size_t)e0.x * 64 + lane];
            float2 v1 = x2[(size_t)e1.x * 64 + lane];
            float2 v2 = x2[(size_t)e2.x * 64 + lane];
            float2 v3 = x2[(size_t)e3.x * 64 + lane];
            float c0 = __int_as_float(e0.y), c1 = __int_as_float(e1.y);
            float cc = __int_as_float(e2.y), c3 = __int_as_float(e3.y);
            a0 = fmaf(v0.x, c0, a0); a1 = fmaf(v0.y, c0, a1);
            a0 = fmaf(v1.x, c1, a0); a1 = fmaf(v1.y, c1, a1);
            a0 = fmaf(v2.x, cc, a0); a1 = fmaf(v2.y, cc, a1);
            a0 = fmaf(v3.x, c3, a0); a1 = fmaf(v3.y, c3, a1);
        }
        for (; j < end; ++j) {
            int2 e = eb[j];
            float2 v = x2[(size_t)e.x * 64 + lane];
            float c = __int_as_float(e.y);
            a0 = fmaf(v.x, c, a0); a1 = fmaf(v.y, c, a1);
        }
        // bf16 hi/lo split; row layout: [hi 128 bf16][lo 128 bf16] = 512B
        unsigned short h0 = f2b(a0), h1 = f2b(a1);
        unsigned short q0 = f2b(a0 - b2f(h0)), q1 = f2b(a1 - b2f(h1));
        ushort2* rowp = (ushort2*)((char*)aggx + (size_t)node * 512);
        rowp[lane] = make_ushort2(h0, h1);        // hi: k = 2*lane, 2*lane+1
        rowp[64 + lane] = make_ushort2(q0, q1);   // lo
    }
}

// ---------------- MFMA GEMM: d_out(bf16 hi/lo rows) @ W -> d_out fp32 ----------
// 4 waves/block, wave w owns rows row0+w*16..+15. Per wave: load its 8 A-frags
// to regs, then 8 col-tiles x 4 k-tiles x 3 MFMAs (hi*hi, lo*hi, hi*lo).
// In-place safe: wave reads only its own rows (into regs, data-dep-ordered
// before its stores); no other wave touches them. Fused BN column stats.
__global__ __launch_bounds__(256) void gemm_mfma(float* __restrict__ out,
                                                 const bf16x8* __restrict__ Whi,
                                                 const bf16x8* __restrict__ Wlo,
                                                 float* __restrict__ colsum,
                                                 float* __restrict__ colsumsq) {
    __shared__ float sps[4][128], spq[4][128];
    int tid = threadIdx.x;
    int w = tid >> 6;
    int l = tid & 63;
    int row0 = blockIdx.x * 64;

    // A-fragment loads: lane l -> row row0+w*16+(l&15), k = t*32+(l>>4)*8 .. +7
    int arow = row0 + w * 16 + (l & 15);
    if (arow >= N_NODES) arow = N_NODES - 1;  // clamp; masked at write/stats
    const char* abase = (const char*)out + (size_t)arow * 512;
    int ao = (l >> 4) << 4;  // byte offset of 8-bf16 group
    bf16x8 ahi[4], alo[4];
#pragma unroll
    for (int t = 0; t < 4; ++t) {
        ahi[t] = *(const bf16x8*)(abase + t * 64 + ao);
        alo[t] = *(const bf16x8*)(abase + 256 + t * 64 + ao);
    }

    int rbase = row0 + w * 16 + ((l >> 4) << 2);  // C/D: row=(l>>4)*4+j
#pragma unroll
    for (int c = 0; c < 8; ++c) {
        f32x4 acc = {0.f, 0.f, 0.f, 0.f};
#pragma unroll
        for (int t = 0; t < 4; ++t) {
            bf16x8 bh = Whi[(t * 8 + c) * 64 + l];
            bf16x8 bl = Wlo[(t * 8 + c) * 64 + l];
            acc = __builtin_amdgcn_mfma_f32_16x16x32_bf16(ahi[t], bh, acc, 0, 0, 0);
            acc = __builtin_amdgcn_mfma_f32_16x16x32_bf16(alo[t], bh, acc, 0, 0, 0);
            acc = __builtin_amdgcn_mfma_f32_16x16x32_bf16(ahi[t], bl, acc, 0, 0, 0);
        }
        int col = c * 16 + (l & 15);
        float ps = 0.f, pq = 0.f;
#pragma unroll
        for (int j = 0; j < 4; ++j) {
            int orow = rbase + j;
            float v = acc[j];
            if (orow < N_NODES) {
                out[(size_t)orow * 128 + col] = v;
                ps += v;
                pq += v * v;
            }
        }
        // reduce the 4 lanes sharing this col (l, l^16, l^32, l^48)
        ps += __shfl_xor(ps, 16); pq += __shfl_xor(pq, 16);
        ps += __shfl_xor(ps, 32); pq += __shfl_xor(pq, 32);
        if (l < 16) { sps[w][c * 16 + l] = ps; spq[w][c * 16 + l] = pq; }
    }
    __syncthreads();
    if (tid < 128) {
        float s = sps[0][tid] + sps[1][tid] + sps[2][tid] + sps[3][tid];
        float q = spq[0][tid] + spq[1][tid] + spq[2][tid] + spq[3][tid];
        atomicAdd(&colsum[tid], s);
        atomicAdd(&colsumsq[tid], q);
    }
}

// ---------------- BN params (b cancels exactly in BatchNorm) ----------------
__global__ void finalize_bn(const float* __restrict__ colsum,
                            const float* __restrict__ colsumsq,
                            const float* __restrict__ gamma,
                            const float* __restrict__ beta,
                            float* __restrict__ scale, float* __restrict__ shift) {
    int c = threadIdx.x;
    float mean = colsum[c] * (1.0f / N_NODES);
    float var = colsumsq[c] * (1.0f / N_NODES) - mean * mean;
    float sc = gamma[c] * rsqrtf(var + BN_EPS);
    scale[c] = sc;
    shift[c] = beta[c] - mean * sc;
}

// ---------------- normalize + ReLU (in place on d_out) ----------------
__global__ __launch_bounds__(256) void normalize_relu(float* __restrict__ out,
                                                      const float* __restrict__ scale,
                                                      const float* __restrict__ shift) {
    const int total = N_NODES * 32;  // float4 count
    float4* o4 = (float4*)out;
    const float4* sc4 = (const float4*)scale;
    const float4* sh4 = (const float4*)shift;
    for (int i = blockIdx.x * blockDim.x + threadIdx.x; i < total;
         i += gridDim.x * blockDim.x) {
        int cg = i & 31;
        float4 v = o4[i];
        float4 sc = sc4[cg];
        float4 sh = sh4[cg];
        v.x = fmaxf(fmaf(v.x, sc.x, sh.x), 0.f);
        v.y = fmaxf(fmaf(v.y, sc.y, sh.y), 0.f);
        v.z = fmaxf(fmaf(v.z, sc.z, sh.z), 0.f);
        v.w = fmaxf(fmaf(v.w, sc.w, sh.w), 0.f);
        o4[i] = v;
    }
}

extern "C" void kernel_launch(void* const* d_in, const int* in_sizes, int n_in,
                              void* d_out, int out_size, void* d_ws, size_t ws_size,
                              hipStream_t stream) {
    const float* x = (const float*)d_in[0];
    const float* Wm = (const float*)d_in[1];
    // d_in[2] = b : cancels exactly in BatchNorm -> unused
    const float* gamma = (const float*)d_in[3];
    const float* beta = (const float*)d_in[4];
    const void* ei = d_in[5];

    float* out = (float*)d_out;  // bf16 hi/lo agg rows, then fp32 final

    // workspace layout
    int2* eb = (int2*)d_ws;                     // E pairs (6.4 MB)
    bf16x8* Whi = (bf16x8*)(eb + N_EDGES);      // 2048 frags (32 KB)
    bf16x8* Wlo = Whi + 2048;                   // 32 KB
    int* deg = (int*)(Wlo + 2048);              // N
    int* rp = deg + N_NODES;                    // N+1
    int* fp = rp + N_NODES + 1;                 // N
    int* bsum = fp + N_NODES;                   // 128
    float* dis = (float*)(bsum + 128);          // N
    float* colsum = dis + N_NODES;              // 128
    float* colsumsq = colsum + 128;             // 128
    float* scale = colsumsq + 128;              // 128
    float* shift = scale + 128;                 // 128
    int* flag = (int*)(shift + 128);            // 1

    hipMemsetAsync(deg, 0, (size_t)N_NODES * sizeof(int), stream);
    hipMemsetAsync(colsum, 0, 256 * sizeof(float), stream);

    detect_i64<<<1, 256, 0, stream>>>((const unsigned int*)ei, flag);
    count_deg_i<<<2048, 256, 0, stream>>>(ei, flag, deg);
    scan1<<<SCAN_NB, 256, 0, stream>>>(deg, rp, bsum);
    scan2<<<1, 128, 0, stream>>>(bsum, rp);
    scan3<<<(N_NODES + 255) / 256, 256, 0, stream>>>(rp, bsum, fp, deg, dis);
    fill_csr<<<2048, 256, 0, stream>>>(ei, flag, fp, dis, eb);
    prep_w<<<1, 256, 0, stream>>>(Wm, Whi, Wlo);
    gather_x<<<2048, 256, 0, stream>>>(rp, eb, dis, x, d_out);
    gemm_mfma<<<(N_NODES + 63) / 64, 256, 0, stream>>>(out, Whi, Wlo, colsum,
                                                       colsumsq);
    finalize_bn<<<1, 128, 0, stream>>>(colsum, colsumsq, gamma, beta, scale, shift);
    normalize_relu<<<2048, 256, 0, stream>>>(out, scale, shift);
}